// Round 1
// baseline (683.124 us; speedup 1.0000x reference)
//
#include <hip/hip_runtime.h>

#define IMG_W 512
#define IMG_H 512
#define TH 64
#define NIMG 192

__global__ void zero_ws_kernel(double* ws) {
  if (threadIdx.x < 2) ws[threadIdx.x] = 0.0;
}

__global__ __launch_bounds__(256) void ssim_mse_kernel(
    const float* __restrict__ recon, const float* __restrict__ orig,
    double* __restrict__ ws) {
  constexpr float C1 = 4.0e-4f;   // (0.01*2)^2
  constexpr float C2 = 3.6e-3f;   // (0.03*2)^2

  const int t = threadIdx.x;
  const int c0 = 2 * t;                      // thread owns cols c0, c0+1
  const size_t ibase = (size_t)blockIdx.y * (IMG_W * IMG_H);
  const int r0 = blockIdx.x * TH;            // block owns rows [r0, r0+TH)
  const float* __restrict__ xi = recon + ibase;
  const float* __restrict__ yi = orig + ibase;

  // Gaussian 1D weights (match reference: expf in f32, normalized in f32)
  float w[11];
  {
    float s = 0.f;
#pragma unroll
    for (int i = 0; i < 11; ++i) {
      float d = (float)(i - 5);
      w[i] = expf(-d * d * (1.0f / 4.5f));   // 2*sigma^2 = 4.5
      s += w[i];
    }
    float inv = 1.0f / s;
#pragma unroll
    for (int i = 0; i < 11; ++i) w[i] *= inv;
  }

  // 4 aligned float4 loads per signal cover cols [c0-8, c0+8); clamp addresses,
  // mask values (zero-padding semantics). Window actually needs [c0-5, c0+6].
  int coff[4];
#pragma unroll
  for (int j = 0; j < 4; ++j) {
    int cj = c0 - 8 + 4 * j;
    cj = cj < 0 ? 0 : cj;
    cj = cj > IMG_W - 4 ? IMG_W - 4 : cj;
    coff[j] = cj;
  }
  bool mok[16];
#pragma unroll
  for (int i = 0; i < 16; ++i) mok[i] = (unsigned)(c0 - 8 + i) < (unsigned)IMG_W;

  // history of horizontal conv results: [row][signal][owned col]
  // signals: conv(x), conv(y), conv(xx), conv(yy), conv(xy)
  float hist[12][5][2];
#pragma unroll
  for (int j = 0; j < 12; ++j)
#pragma unroll
    for (int s5 = 0; s5 < 5; ++s5)
#pragma unroll
      for (int o = 0; o < 2; ++o) hist[j][s5][o] = 0.f;

  float mse_acc = 0.f, ssim_acc = 0.f;

#pragma unroll 1
  for (int it = 0; it < (TH + 10) / 2; ++it) {
    // shift history down by 2 rows (all indices compile-time)
#pragma unroll
    for (int j = 0; j < 10; ++j)
#pragma unroll
      for (int s5 = 0; s5 < 5; ++s5)
#pragma unroll
        for (int o = 0; o < 2; ++o) hist[j][s5][o] = hist[j + 2][s5][o];

    // load + horizontal conv for 2 new input rows
#pragma unroll
    for (int rr = 0; rr < 2; ++rr) {
      const int ri = r0 - 5 + 2 * it + rr;
      float xl[16], yl[16];
      if (ri >= 0 && ri < IMG_H) {            // uniform branch per block
        const float* xrow = xi + (size_t)ri * IMG_W;
        const float* yrow = yi + (size_t)ri * IMG_W;
#pragma unroll
        for (int j = 0; j < 4; ++j) {
          float4 xv = *reinterpret_cast<const float4*>(xrow + coff[j]);
          float4 yv = *reinterpret_cast<const float4*>(yrow + coff[j]);
          xl[4 * j + 0] = xv.x; xl[4 * j + 1] = xv.y;
          xl[4 * j + 2] = xv.z; xl[4 * j + 3] = xv.w;
          yl[4 * j + 0] = yv.x; yl[4 * j + 1] = yv.y;
          yl[4 * j + 2] = yv.z; yl[4 * j + 3] = yv.w;
        }
#pragma unroll
        for (int i = 3; i <= 14; ++i) {       // only window-used elements
          xl[i] = mok[i] ? xl[i] : 0.f;
          yl[i] = mok[i] ? yl[i] : 0.f;
        }
        // fused MSE on owned pixels (each image pixel counted exactly once)
        if (ri >= r0 && ri < r0 + TH) {
          float d0 = xl[8] - yl[8];
          float d1 = xl[9] - yl[9];
          mse_acc += d0 * d0;
          mse_acc += d1 * d1;
        }
      } else {
#pragma unroll
        for (int i = 0; i < 16; ++i) { xl[i] = 0.f; yl[i] = 0.f; }
      }
      // horizontal 11-tap conv of 5 signals for 2 owned cols
#pragma unroll
      for (int o = 0; o < 2; ++o) {
        float sx = 0.f, sy = 0.f, sxx = 0.f, syy = 0.f, sxy = 0.f;
#pragma unroll
        for (int k = 0; k < 11; ++k) {
          float xv = xl[3 + o + k], yv = yl[3 + o + k];
          float wk = w[k];
          sx  += wk * xv;
          sy  += wk * yv;
          sxx += wk * (xv * xv);   // products CSE'd across o by compiler
          syy += wk * (yv * yv);
          sxy += wk * (xv * yv);
        }
        hist[10 + rr][0][o] = sx;
        hist[10 + rr][1][o] = sy;
        hist[10 + rr][2][o] = sxx;
        hist[10 + rr][3][o] = syy;
        hist[10 + rr][4][o] = sxy;
      }
    }

    // vertical conv + SSIM formula for 2 output rows once history is full
    if (it >= 5) {
#pragma unroll
      for (int rr = 0; rr < 2; ++rr) {
#pragma unroll
        for (int o = 0; o < 2; ++o) {
          float mu1 = 0.f, mu2 = 0.f, vxx = 0.f, vyy = 0.f, vxy = 0.f;
#pragma unroll
          for (int k = 0; k < 11; ++k) {
            float wk = w[k];
            mu1 += wk * hist[rr + k][0][o];
            mu2 += wk * hist[rr + k][1][o];
            vxx += wk * hist[rr + k][2][o];
            vyy += wk * hist[rr + k][3][o];
            vxy += wk * hist[rr + k][4][o];
          }
          float mu1sq = mu1 * mu1, mu2sq = mu2 * mu2, mu12 = mu1 * mu2;
          float s1 = vxx - mu1sq, s2 = vyy - mu2sq, s12 = vxy - mu12;
          float num = (2.f * mu12 + C1) * (2.f * s12 + C2);
          float den = (mu1sq + mu2sq + C1) * (s1 + s2 + C2);
          ssim_acc += num / den;
        }
      }
    }
  }

  // block reduction: wave shuffle -> LDS -> one f64 atomic pair per block
#pragma unroll
  for (int off = 32; off > 0; off >>= 1) {
    ssim_acc += __shfl_down(ssim_acc, off);
    mse_acc  += __shfl_down(mse_acc, off);
  }
  __shared__ float red[8];
  const int wv = t >> 6;
  if ((t & 63) == 0) { red[2 * wv] = ssim_acc; red[2 * wv + 1] = mse_acc; }
  __syncthreads();
  if (t == 0) {
    float ssum = red[0] + red[2] + red[4] + red[6];
    float msum = red[1] + red[3] + red[5] + red[7];
    atomicAdd(ws, (double)ssum);
    atomicAdd(ws + 1, (double)msum);
  }
}

__global__ void finalize_kernel(const double* __restrict__ ws,
                                float* __restrict__ out) {
  if (threadIdx.x == 0) {
    const double N = 50331648.0;  // 64*3*512*512
    double ssim = ws[0] / N;
    double mse  = ws[1] / N;
    out[0] = (float)(0.7 * mse + 0.3 * (1.0 - ssim));
  }
}

extern "C" void kernel_launch(void* const* d_in, const int* in_sizes, int n_in,
                              void* d_out, int out_size, void* d_ws, size_t ws_size,
                              hipStream_t stream) {
  const float* recon = (const float*)d_in[0];
  const float* orig  = (const float*)d_in[1];
  double* ws = (double*)d_ws;
  float* out = (float*)d_out;

  hipLaunchKernelGGL(zero_ws_kernel, dim3(1), dim3(64), 0, stream, ws);
  dim3 grid(IMG_H / TH, NIMG, 1);
  hipLaunchKernelGGL(ssim_mse_kernel, grid, dim3(256), 0, stream, recon, orig, ws);
  hipLaunchKernelGGL(finalize_kernel, dim3(1), dim3(64), 0, stream, ws, out);
}